// Round 15
// baseline (169.063 us; speedup 1.0000x reference)
//
#include <hip/hip_runtime.h>

#define D 128
#define BE 4096     // edges per sort block
#define SC 5120     // brec records per bucket (Poisson(4096), 16-sigma headroom)
#define LROW 136    // padded LDS row stride in ushorts (272 B)

typedef __attribute__((ext_vector_type(8))) short bf16x8;
typedef __attribute__((ext_vector_type(4))) float f32x4;
typedef __attribute__((ext_vector_type(8))) unsigned short u16x8;

// ---------- bf16 helpers (manual, RNE) ----------
__device__ inline unsigned short f2bf(float f) {
    unsigned u = __float_as_uint(f);
    return (unsigned short)((u + 0x7fff + ((u >> 16) & 1)) >> 16);
}
__device__ inline float bf2f(unsigned short s) {
    return __uint_as_float((unsigned)s << 16);
}
__device__ inline bf16x8 cvt8(const float* __restrict__ p) {
    float4 a = *(const float4*)p;
    float4 b = *(const float4*)(p + 4);
    bf16x8 r;
    r[0] = (short)f2bf(a.x); r[1] = (short)f2bf(a.y);
    r[2] = (short)f2bf(a.z); r[3] = (short)f2bf(a.w);
    r[4] = (short)f2bf(b.x); r[5] = (short)f2bf(b.y);
    r[6] = (short)f2bf(b.z); r[7] = (short)f2bf(b.w);
    return r;
}

// ---------- prep: W->bf16; zero bcnt, gcnt, degree bins ----------
__global__ void k_prep(const float* __restrict__ W1, const float* __restrict__ W2,
                       unsigned short* __restrict__ Wb1, unsigned short* __restrict__ Wb2,
                       int* __restrict__ bcnt, int* __restrict__ gcnt,
                       int* __restrict__ dbins, int NBK) {
    int i = blockIdx.x * 256 + threadIdx.x;
    if (i < D * D) { Wb1[i] = f2bf(W1[i]); Wb2[i] = f2bf(W2[i]); }
    if (i < NBK) bcnt[i] = 0;
    if (i == D * D) *gcnt = 0;
    if (i < 32) dbins[i] = 0;
}

// ---------- gemm1: 64-row tile, 1 B-frag per wave (fills the grid) ---------
// C = W·x^T, mfma_f32_16x16x32_bf16; C layout (m89): col(lane&15)=node,
// row=(lane>>4)*4+reg. #pragma unroll 1: round-3 hoist/spill lesson.

__device__ inline void gemm1_tile64(const float* __restrict__ xx,
                                    const unsigned short* __restrict__ Wb,
                                    unsigned short* __restrict__ g,
                                    int N, int tile, int t) {
    int w = t >> 6, l = t & 63;
    int r16 = l & 15, g4 = l >> 4;
    int row = tile * 64 + w * 16 + r16;
    int cr = (row < N) ? row : N - 1;
    f32x4 acc[8] = {};
    const unsigned short* wr = Wb + r16 * D + g4 * 8;
#pragma unroll 1
    for (int ks = 0; ks < 4; ks++) {
        bf16x8 b = cvt8(xx + (size_t)cr * D + g4 * 8 + ks * 32);
#pragma unroll
        for (int jt = 0; jt < 8; jt++) {
            bf16x8 a = *(const bf16x8*)(wr + jt * 16 * D + ks * 32);
            acc[jt] = __builtin_amdgcn_mfma_f32_16x16x32_bf16(a, b, acc[jt], 0, 0, 0);
        }
    }
    if (row < N) {
#pragma unroll
        for (int jt = 0; jt < 8; jt++) {
            ushort4 o = { f2bf(acc[jt][0]), f2bf(acc[jt][1]),
                          f2bf(acc[jt][2]), f2bf(acc[jt][3]) };
            *(ushort4*)&g[(size_t)row * D + jt * 16 + g4 * 4] = o;
        }
    }
}

// ---------- K1: counting-sort (1/9 of blocks) || ALL gemm1 tiles (8/9) -----
// Sort: 4096 edges -> LDS sort by bucket dst>>9, reserve ranges with <=NBK
// atomics, stream out coalesced. Record=(src<<9)|(dst&511).
// NOTE: harness delivers integer inputs as int32 (edge_index arrives as int*).

__global__ __launch_bounds__(256) void k_sort_gemm1(
        const int* __restrict__ ei, int* __restrict__ bcnt, unsigned* __restrict__ brec,
        const float* __restrict__ x, const unsigned short* __restrict__ Wb1,
        unsigned short* __restrict__ g, int N, int E, int nt64, int sortB, int NBK) {
    int bid = blockIdx.x;
    if (bid % 9 == 8) {                         // ---- sort role ----
        __shared__ unsigned srt[BE];            // 16 KB
        __shared__ unsigned char bko[BE];       // 4 KB
        __shared__ int hist[256];
        __shared__ int pfx[256];
        __shared__ int gbase[256];
        __shared__ int cur[256];
        int f = bid / 9;
        if (f >= sortB) return;
        int t = threadIdx.x;
        int e0 = f * BE;
        int n = E - e0; if (n > BE) n = BE;
        hist[t] = 0; cur[t] = 0;
        __syncthreads();
        unsigned rec[16]; int mb[16];
#pragma unroll
        for (int j = 0; j < 16; j++) {
            int e = e0 + j * 256 + t;           // coalesced
            if (e < E) {
                int s = ei[e], d = ei[E + e];
                rec[j] = ((unsigned)s << 9) | (unsigned)(d & 511);
                mb[j] = d >> 9;
                atomicAdd(&hist[mb[j]], 1);
            } else mb[j] = -1;
        }
        __syncthreads();
        int v = hist[t];
        pfx[t] = v;
        __syncthreads();
        for (int dd = 1; dd < 256; dd <<= 1) {
            int xv = (t >= dd) ? pfx[t - dd] : 0;
            __syncthreads();
            pfx[t] += xv;
            __syncthreads();
        }
        pfx[t] -= v;                            // exclusive prefix
        if (v > 0 && t < NBK) gbase[t] = atomicAdd(&bcnt[t], v);
        __syncthreads();
#pragma unroll
        for (int j = 0; j < 16; j++) {
            if (mb[j] >= 0) {
                int p = pfx[mb[j]] + atomicAdd(&cur[mb[j]], 1);
                srt[p] = rec[j];
                bko[p] = (unsigned char)mb[j];
            }
        }
        __syncthreads();
        for (int i = t; i < n; i += 256) {      // bucket-ordered -> coalesced
            int b = bko[i];
            int pos = gbase[b] + (i - pfx[b]);
            if (pos < SC) brec[(size_t)b * SC + pos] = srt[i];
        }
    } else {                                    // ---- gemm1 role ----
        int gid = (bid / 9) * 8 + (bid % 9);
        if (gid >= nt64) return;
        gemm1_tile64(x, Wb1, g, N, gid, threadIdx.x);
    }
}

// ---------- build: one block per bucket -> dense CSR + degree histogram ----
__global__ __launch_bounds__(256) void k_build(const int* __restrict__ bcnt,
                                               const unsigned* __restrict__ brec,
                                               int* __restrict__ cnt,
                                               int* __restrict__ rp,
                                               int* __restrict__ col,
                                               int* __restrict__ gcnt,
                                               int* __restrict__ dbins, int N) {
    __shared__ int c512[512];
    __shared__ int base512[512];
    __shared__ int psc[256];
    __shared__ int dh[32];
    __shared__ int bksum;
    int b = blockIdx.x, t = threadIdx.x;
    c512[t] = 0; c512[t + 256] = 0;
    if (t < 32) dh[t] = 0;
    __syncthreads();
    int total = bcnt[b]; if (total > SC) total = SC;
    for (int i = t; i < total; i += 256)
        atomicAdd(&c512[brec[(size_t)b * SC + i] & 511], 1);
    __syncthreads();
    int d0 = c512[2 * t], d1 = c512[2 * t + 1];
    int pair = d0 + d1;
    psc[t] = pair;
    __syncthreads();
    for (int dd = 1; dd < 256; dd <<= 1) {
        int xv = (t >= dd) ? psc[t - dd] : 0;
        __syncthreads();
        psc[t] += xv;
        __syncthreads();
    }
    int pexc = psc[t] - pair;
    if (t == 255) bksum = atomicAdd(gcnt, psc[255]);
    __syncthreads();
    int gb = bksum;
    base512[2 * t]     = gb + pexc;
    base512[2 * t + 1] = gb + pexc + d0;
    c512[2 * t] = 0; c512[2 * t + 1] = 0;
    __syncthreads();
    for (int i = t; i < total; i += 256) {
        unsigned rec = brec[(size_t)b * SC + i];
        int dl = rec & 511;
        int p = atomicAdd(&c512[dl], 1);
        col[base512[dl] + p] = (int)(rec >> 9);
    }
    __syncthreads();
#pragma unroll
    for (int k = 0; k < 2; k++) {
        int dl = t + k * 256;
        int node = b * 512 + dl;
        if (node < N) {
            int dg = c512[dl];
            cnt[node] = dg; rp[node] = base512[dl];
            atomicAdd(&dh[dg > 31 ? 31 : dg], 1);   // degree histogram
        }
    }
    __syncthreads();
    if (t < 32 && dh[t] > 0) atomicAdd(&dbins[t], dh[t]);
}

// ---------- scan32: dbins -> exclusive bases (then used as cursors) --------
__global__ void k_scan32(int* __restrict__ dbins) {
    if (threadIdx.x == 0) {
        int run = 0;
        for (int i = 0; i < 32; i++) { int v = dbins[i]; dbins[i] = run; run += v; }
    }
}

// ---------- scatter: perm = nodes counting-sorted by degree ----------------
// Per block: 512 nodes, LDS hist, one global atomicAdd per (block,bin)
// reserves a range, local ranks place nodes. Blocks of 16 perm-adjacent
// nodes then have equal degree (+-1) -> no barrier tail in k_agg1_g2.

__global__ __launch_bounds__(256) void k_scatter(const int* __restrict__ cnt,
                                                 int* __restrict__ dbins,
                                                 int* __restrict__ perm, int N) {
    __shared__ int lh[32], lbase[32], lcur[32];
    int b = blockIdx.x, t = threadIdx.x;
    if (t < 32) { lh[t] = 0; lcur[t] = 0; }
    __syncthreads();
    int bin[2];
#pragma unroll
    for (int k = 0; k < 2; k++) {
        int node = b * 512 + k * 256 + t;
        if (node < N) {
            int d = cnt[node];
            bin[k] = d > 31 ? 31 : d;
            atomicAdd(&lh[bin[k]], 1);
        } else bin[k] = -1;
    }
    __syncthreads();
    if (t < 32 && lh[t] > 0) lbase[t] = atomicAdd(&dbins[t], lh[t]);
    __syncthreads();
#pragma unroll
    for (int k = 0; k < 2; k++) {
        if (bin[k] >= 0) {
            int r = atomicAdd(&lcur[bin[k]], 1);
            perm[lbase[bin[k]] + r] = b * 512 + k * 256 + t;
        }
    }
}

// ---------- fused agg1 + row-local gemm2 (degree-balanced blocks) ----------
// Agg: 16-lane group per node (r13 proven shape, full concurrency), nodes
// taken via perm so the block's 16 nodes share a degree -> barrier tail ~0.
// h -> 4.3 KB LDS tile; one barrier; 2jt x 4ks MFMAs with W2 (L2-hot);
// g2 written dis-folded. h never touches HBM.

__global__ __launch_bounds__(256) void k_agg1_g2(
        const unsigned short* __restrict__ gtab, const int* __restrict__ cnt,
        const int* __restrict__ rp, const int* __restrict__ col,
        const int* __restrict__ perm,
        const float* __restrict__ b1, const unsigned short* __restrict__ Wb2,
        unsigned short* __restrict__ g2, int N) {
    __shared__ __align__(16) unsigned short hl[16 * LROW];   // 4.3 KB
    int t = threadIdx.x, grp = t >> 4, l16 = t & 15;
    int n0 = blockIdx.x * 16;
    int pos = n0 + grp;
    bool valid = (pos < N);
    int node = valid ? perm[pos] : 0;
    const u16x8* G = (const u16x8*)gtab;

    int deg = valid ? cnt[node] : 0;
    float disv = rsqrtf((float)(deg + 1));
    float acc[8];
    {
        u16x8 s = G[(size_t)node * 16 + l16];   // self-loop term (x dis_v)
#pragma unroll
        for (int j = 0; j < 8; j++) acc[j] = bf2f(s[j]) * disv;
    }
    const int* cb = col + (valid ? rp[node] : 0);
    int i = 0;
    for (; i + 3 < deg; i += 4) {
        int u0 = cb[i], u1 = cb[i + 1], u2 = cb[i + 2], u3 = cb[i + 3];
        u16x8 m0 = G[(size_t)u0 * 16 + l16];
        u16x8 m1 = G[(size_t)u1 * 16 + l16];
        u16x8 m2 = G[(size_t)u2 * 16 + l16];
        u16x8 m3 = G[(size_t)u3 * 16 + l16];
        float d0 = rsqrtf((float)(cnt[u0] + 1));
        float d1 = rsqrtf((float)(cnt[u1] + 1));
        float d2 = rsqrtf((float)(cnt[u2] + 1));
        float d3 = rsqrtf((float)(cnt[u3] + 1));
#pragma unroll
        for (int j = 0; j < 8; j++)
            acc[j] += (bf2f(m0[j]) * d0 + bf2f(m1[j]) * d1)
                    + (bf2f(m2[j]) * d2 + bf2f(m3[j]) * d3);
    }
    for (; i < deg; i++) {
        int u = cb[i];
        u16x8 m = G[(size_t)u * 16 + l16];
        float du = rsqrtf((float)(cnt[u] + 1));
#pragma unroll
        for (int j = 0; j < 8; j++) acc[j] += bf2f(m[j]) * du;
    }
    {
        const float4* B4 = (const float4*)b1;
        float4 bb0 = B4[l16 * 2], bb1 = B4[l16 * 2 + 1];
        float r[8];
        r[0] = fmaf(acc[0], disv, bb0.x); r[1] = fmaf(acc[1], disv, bb0.y);
        r[2] = fmaf(acc[2], disv, bb0.z); r[3] = fmaf(acc[3], disv, bb0.w);
        r[4] = fmaf(acc[4], disv, bb1.x); r[5] = fmaf(acc[5], disv, bb1.y);
        r[6] = fmaf(acc[6], disv, bb1.z); r[7] = fmaf(acc[7], disv, bb1.w);
        u16x8 hv;
#pragma unroll
        for (int j = 0; j < 8; j++)
            hv[j] = valid ? f2bf(fmaxf(r[j], 0.f)) : (unsigned short)0;
        *(u16x8*)&hl[grp * LROW + l16 * 8] = hv;
    }
    __syncthreads();

    // ---- mini-gemm2: B-frags = LDS h rows (node = perm[n0 + (lane&15)]) ----
    int w = t >> 6, l = t & 63;
    int r16 = l & 15, g4 = l >> 4;
    f32x4 a0 = {}, a1 = {};
    const unsigned short* wr = Wb2 + r16 * D + g4 * 8;
    int xb = r16 * LROW + g4 * 8;
#pragma unroll 1
    for (int ks = 0; ks < 4; ks++) {
        bf16x8 b = *(const bf16x8*)&hl[xb + ks * 32];
        bf16x8 A0 = *(const bf16x8*)(wr + (2 * w) * 16 * D + ks * 32);
        bf16x8 A1 = *(const bf16x8*)(wr + (2 * w + 1) * 16 * D + ks * 32);
        a0 = __builtin_amdgcn_mfma_f32_16x16x32_bf16(A0, b, a0, 0, 0, 0);
        a1 = __builtin_amdgcn_mfma_f32_16x16x32_bf16(A1, b, a1, 0, 0, 0);
    }
    int pos2 = n0 + r16;
    if (pos2 < N) {
        int orow = perm[pos2];
        float dv = rsqrtf((float)(cnt[orow] + 1));
        ushort4 o0 = { f2bf(a0[0] * dv), f2bf(a0[1] * dv),
                       f2bf(a0[2] * dv), f2bf(a0[3] * dv) };
        ushort4 o1 = { f2bf(a1[0] * dv), f2bf(a1[1] * dv),
                       f2bf(a1[2] * dv), f2bf(a1[3] * dv) };
        *(ushort4*)&g2[(size_t)orow * D + (2 * w) * 16 + g4 * 4] = o0;
        *(ushort4*)&g2[(size_t)orow * D + (2 * w + 1) * 16 + g4 * 4] = o1;
    }
}

// ---------- agg2: final aggregation -> fp32 out (r13 proven shape) ---------
__global__ __launch_bounds__(256) void k_agg2(
        const unsigned short* __restrict__ g2, const int* __restrict__ cnt,
        const int* __restrict__ rp, const int* __restrict__ col,
        const float* __restrict__ b2, float* __restrict__ out, int N) {
    int node = blockIdx.x * 16 + (threadIdx.x >> 4);
    if (node >= N) return;
    int l16 = threadIdx.x & 15;
    const u16x8* G = (const u16x8*)g2;
    int deg = cnt[node];
    float acc[8];
    {
        u16x8 s = G[(size_t)node * 16 + l16];
#pragma unroll
        for (int j = 0; j < 8; j++) acc[j] = bf2f(s[j]);
    }
    const int* cb = col + rp[node];
    int i = 0;
    for (; i + 3 < deg; i += 4) {
        int u0 = cb[i], u1 = cb[i + 1], u2 = cb[i + 2], u3 = cb[i + 3];
        u16x8 m0 = G[(size_t)u0 * 16 + l16];
        u16x8 m1 = G[(size_t)u1 * 16 + l16];
        u16x8 m2 = G[(size_t)u2 * 16 + l16];
        u16x8 m3 = G[(size_t)u3 * 16 + l16];
#pragma unroll
        for (int j = 0; j < 8; j++)
            acc[j] += (bf2f(m0[j]) + bf2f(m1[j])) + (bf2f(m2[j]) + bf2f(m3[j]));
    }
    for (; i < deg; i++) {
        u16x8 m = G[(size_t)cb[i] * 16 + l16];
#pragma unroll
        for (int j = 0; j < 8; j++) acc[j] += bf2f(m[j]);
    }
    float disv = rsqrtf((float)(deg + 1));
    const float4* B4 = (const float4*)b2;
    float4 bb0 = B4[l16 * 2], bb1 = B4[l16 * 2 + 1];
    float4 o0, o1;
    o0.x = fmaf(acc[0], disv, bb0.x); o0.y = fmaf(acc[1], disv, bb0.y);
    o0.z = fmaf(acc[2], disv, bb0.z); o0.w = fmaf(acc[3], disv, bb0.w);
    o1.x = fmaf(acc[4], disv, bb1.x); o1.y = fmaf(acc[5], disv, bb1.y);
    o1.z = fmaf(acc[6], disv, bb1.z); o1.w = fmaf(acc[7], disv, bb1.w);
    ((float4*)out)[(size_t)node * 32 + l16 * 2]     = o0;
    ((float4*)out)[(size_t)node * 32 + l16 * 2 + 1] = o1;
}

// ---------- launch ----------

extern "C" void kernel_launch(void* const* d_in, const int* in_sizes, int n_in,
                              void* d_out, int out_size, void* d_ws, size_t ws_size,
                              hipStream_t stream) {
    const float* x  = (const float*)d_in[0];
    const int*   ei = (const int*)d_in[1];
    const float* W1 = (const float*)d_in[2];
    const float* b1 = (const float*)d_in[3];
    const float* W2 = (const float*)d_in[4];
    const float* b2 = (const float*)d_in[5];
    float* out = (float*)d_out;

    int N = in_sizes[0] / D;
    int E = in_sizes[1] / 2;
    int NBK = (N + 511) >> 9;                // buckets of 512 nodes

    // ws: g 25.6 | g2 25.6 | cnt .4 | rp .4 | perm .4 | col 3.2 | Wb .13
    //   | bcnt ~1KB | gcnt | dbins | brec 4  -> ~59.8 MB
    char* w = (char*)d_ws;
    unsigned short* g  = (unsigned short*)w;  size_t off = (size_t)N * D * 2;
    off = (off + 255) & ~(size_t)255;
    unsigned short* g2 = (unsigned short*)(w + off); off += (size_t)N * D * 2;
    off = (off + 255) & ~(size_t)255;
    int* cnt  = (int*)(w + off);             off += (size_t)N * 4;
    off = (off + 255) & ~(size_t)255;
    int* rp   = (int*)(w + off);             off += (size_t)N * 4;
    off = (off + 255) & ~(size_t)255;
    int* perm = (int*)(w + off);             off += (size_t)N * 4;
    off = (off + 255) & ~(size_t)255;
    int* col  = (int*)(w + off);             off += (size_t)E * 4;
    off = (off + 255) & ~(size_t)255;
    unsigned short* Wb1 = (unsigned short*)(w + off); off += (size_t)D * D * 2;
    unsigned short* Wb2 = (unsigned short*)(w + off); off += (size_t)D * D * 2;
    off = (off + 255) & ~(size_t)255;
    int* bcnt = (int*)(w + off);             off += (size_t)NBK * 4;
    off = (off + 255) & ~(size_t)255;
    int* gcnt = (int*)(w + off);             off += 256;
    int* dbins = (int*)(w + off);            off += 256;
    unsigned* brec = (unsigned*)(w + off);   off += (size_t)NBK * SC * 4;

    int nt64 = (N + 63) / 64;                // 1563 gemm1 tiles
    int sortB = (E + BE - 1) / BE;           // 196 sort blocks
    int fb = sortB > (nt64 + 7) / 8 ? sortB : (nt64 + 7) / 8;
    int agg_grid = (N + 15) / 16;

    k_prep<<<(D * D + 511) / 256, 256, 0, stream>>>(W1, W2, Wb1, Wb2, bcnt, gcnt, dbins, NBK);

    // K1: sort (ei -> bcnt,brec)  ||  ALL gemm1 (g = bf16(x @ W1^T), raw)
    k_sort_gemm1<<<9 * fb, 256, 0, stream>>>(ei, bcnt, brec, x, Wb1, g,
                                             N, E, nt64, sortB, NBK);
    // build: brec -> dense CSR + degree histogram
    k_build<<<NBK, 256, 0, stream>>>(bcnt, brec, cnt, rp, col, gcnt, dbins, N);
    // degree-permutation for balanced fused blocks
    k_scan32<<<1, 64, 0, stream>>>(dbins);
    k_scatter<<<NBK, 256, 0, stream>>>(cnt, dbins, perm, N);

    // fused agg1 + row-local gemm2 (degree-balanced): g2 = bf16(dis*(h @ W2^T))
    k_agg1_g2<<<agg_grid, 256, 0, stream>>>(g, cnt, rp, col, perm, b1, Wb2, g2, N);

    // agg2: out = dis_v*(Σ g2[u] + g2[v]) + b2  (fp32) -> d_out
    k_agg2<<<agg_grid, 256, 0, stream>>>(g2, cnt, rp, col, b2, out, N);
}

// Round 16
// 154.349 us; speedup vs baseline: 1.0953x; 1.0953x over previous
//
#include <hip/hip_runtime.h>

#define D 128
#define BE 4096     // edges per sort block
#define SC 5120     // brec records per bucket (Poisson(4096), 16-sigma headroom)
#define LROW 136    // padded LDS row stride in ushorts (272 B)

typedef __attribute__((ext_vector_type(8))) short bf16x8;
typedef __attribute__((ext_vector_type(4))) float f32x4;
typedef __attribute__((ext_vector_type(8))) unsigned short u16x8;

// ---------- bf16 helpers (manual, RNE) ----------
__device__ inline unsigned short f2bf(float f) {
    unsigned u = __float_as_uint(f);
    return (unsigned short)((u + 0x7fff + ((u >> 16) & 1)) >> 16);
}
__device__ inline float bf2f(unsigned short s) {
    return __uint_as_float((unsigned)s << 16);
}
__device__ inline bf16x8 cvt8(const float* __restrict__ p) {
    float4 a = *(const float4*)p;
    float4 b = *(const float4*)(p + 4);
    bf16x8 r;
    r[0] = (short)f2bf(a.x); r[1] = (short)f2bf(a.y);
    r[2] = (short)f2bf(a.z); r[3] = (short)f2bf(a.w);
    r[4] = (short)f2bf(b.x); r[5] = (short)f2bf(b.y);
    r[6] = (short)f2bf(b.z); r[7] = (short)f2bf(b.w);
    return r;
}

// ---------- prep: W1,W2 fp32 -> bf16; zero bucket counters + global base ---
__global__ void k_prep(const float* __restrict__ W1, const float* __restrict__ W2,
                       unsigned short* __restrict__ Wb1, unsigned short* __restrict__ Wb2,
                       int* __restrict__ bcnt, int* __restrict__ gcnt, int NBK) {
    int i = blockIdx.x * 256 + threadIdx.x;
    if (i < D * D) { Wb1[i] = f2bf(W1[i]); Wb2[i] = f2bf(W2[i]); }
    if (i < NBK) bcnt[i] = 0;
    if (i == D * D) *gcnt = 0;
}

// ---------- gemm1: 128-node tile, 32 per wave (r14 proven shape) ----------
// C = W·x^T, mfma_f32_16x16x32_bf16; C layout (m89): col(lane&15)=node,
// row=(lane>>4)*4+reg. Writes g raw (dis_u applied per-edge in agg1).
// #pragma unroll 1 on ks-loop: round-3 hoist/spill lesson.

__device__ inline void gemm1_tile(const float* __restrict__ xx,
                                  const unsigned short* __restrict__ Wb,
                                  unsigned short* __restrict__ g,
                                  int N, int tile, int t) {
    int w = t >> 6, l = t & 63;
    int r16 = l & 15, g4 = l >> 4;
    int base = tile * 128 + w * 32;
    int row0 = base + r16, row1 = row0 + 16;
    int cr0 = (row0 < N) ? row0 : N - 1;
    int cr1 = (row1 < N) ? row1 : N - 1;

    f32x4 acc0[8] = {};
    f32x4 acc1[8] = {};
    const unsigned short* wr = Wb + r16 * D + g4 * 8;

#pragma unroll 1
    for (int ks = 0; ks < 4; ks++) {
        bf16x8 b0 = cvt8(xx + (size_t)cr0 * D + g4 * 8 + ks * 32);
        bf16x8 b1 = cvt8(xx + (size_t)cr1 * D + g4 * 8 + ks * 32);
#pragma unroll
        for (int jt = 0; jt < 8; jt++) {
            bf16x8 a = *(const bf16x8*)(wr + jt * 16 * D + ks * 32);
            acc0[jt] = __builtin_amdgcn_mfma_f32_16x16x32_bf16(a, b0, acc0[jt], 0, 0, 0);
            acc1[jt] = __builtin_amdgcn_mfma_f32_16x16x32_bf16(a, b1, acc1[jt], 0, 0, 0);
        }
    }
#pragma unroll
    for (int tt = 0; tt < 2; tt++) {
        int row = base + tt * 16 + r16;
        if (row < N) {
#pragma unroll
            for (int jt = 0; jt < 8; jt++) {
                f32x4 a = tt ? acc1[jt] : acc0[jt];
                ushort4 o = { f2bf(a[0]), f2bf(a[1]), f2bf(a[2]), f2bf(a[3]) };
                *(ushort4*)&g[(size_t)row * D + jt * 16 + g4 * 4] = o;
            }
        }
    }
}

// ---------- K1: counting-sort (1/9 of blocks) || ALL gemm1 tiles (8/9) -----
// Grid 9*196=1764 blocks (~7/CU): gemm1 fills the machine, sort (~9us of
// LDS-sort + coalesced streams) hides under it. Round-14 lesson: splitting
// gemm1 across two kernels left each at ~588 blocks -> latency-bound.
// Record=(src<<9)|(dst&511); reserve ranges with <=NBK atomics per block.
// NOTE: harness delivers integer inputs as int32 (edge_index arrives as int*).

__global__ __launch_bounds__(256) void k_sort_gemm1(
        const int* __restrict__ ei, int* __restrict__ bcnt, unsigned* __restrict__ brec,
        const float* __restrict__ x, const unsigned short* __restrict__ Wb1,
        unsigned short* __restrict__ g, int N, int E, int ntiles, int sortB, int NBK) {
    int bid = blockIdx.x;
    if (bid % 9 == 8) {                         // ---- sort role ----
        __shared__ unsigned srt[BE];            // 16 KB
        __shared__ unsigned char bko[BE];       // 4 KB
        __shared__ int hist[256];
        __shared__ int pfx[256];
        __shared__ int gbase[256];
        __shared__ int cur[256];
        int f = bid / 9;
        if (f >= sortB) return;
        int t = threadIdx.x;
        int e0 = f * BE;
        int n = E - e0; if (n > BE) n = BE;
        hist[t] = 0; cur[t] = 0;
        __syncthreads();
        unsigned rec[16]; int mb[16];
#pragma unroll
        for (int j = 0; j < 16; j++) {
            int e = e0 + j * 256 + t;           // coalesced
            if (e < E) {
                int s = ei[e], d = ei[E + e];
                rec[j] = ((unsigned)s << 9) | (unsigned)(d & 511);
                mb[j] = d >> 9;
                atomicAdd(&hist[mb[j]], 1);
            } else mb[j] = -1;
        }
        __syncthreads();
        int v = hist[t];
        pfx[t] = v;
        __syncthreads();
        for (int dd = 1; dd < 256; dd <<= 1) {
            int xv = (t >= dd) ? pfx[t - dd] : 0;
            __syncthreads();
            pfx[t] += xv;
            __syncthreads();
        }
        pfx[t] -= v;                            // exclusive prefix
        if (v > 0 && t < NBK) gbase[t] = atomicAdd(&bcnt[t], v);
        __syncthreads();
#pragma unroll
        for (int j = 0; j < 16; j++) {
            if (mb[j] >= 0) {
                int p = pfx[mb[j]] + atomicAdd(&cur[mb[j]], 1);
                srt[p] = rec[j];
                bko[p] = (unsigned char)mb[j];
            }
        }
        __syncthreads();
        for (int i = t; i < n; i += 256) {      // bucket-ordered -> coalesced
            int b = bko[i];
            int pos = gbase[b] + (i - pfx[b]);
            if (pos < SC) brec[(size_t)b * SC + pos] = srt[i];
        }
    } else {                                    // ---- gemm1 role ----
        int gid = (bid / 9) * 8 + (bid % 9);
        if (gid >= ntiles) return;
        gemm1_tile(x, Wb1, g, N, gid, threadIdx.x);
    }
}

// ---------- build: one block per bucket -> dense CSR (col, rp, cnt) --------
__global__ __launch_bounds__(256) void k_build(const int* __restrict__ bcnt,
                                               const unsigned* __restrict__ brec,
                                               int* __restrict__ cnt,
                                               int* __restrict__ rp,
                                               int* __restrict__ col,
                                               int* __restrict__ gcnt, int N) {
    __shared__ int c512[512];
    __shared__ int base512[512];
    __shared__ int psc[256];
    __shared__ int bksum;
    int b = blockIdx.x, t = threadIdx.x;
    c512[t] = 0; c512[t + 256] = 0;
    __syncthreads();
    int total = bcnt[b]; if (total > SC) total = SC;
    for (int i = t; i < total; i += 256)
        atomicAdd(&c512[brec[(size_t)b * SC + i] & 511], 1);
    __syncthreads();
    int d0 = c512[2 * t], d1 = c512[2 * t + 1];
    int pair = d0 + d1;
    psc[t] = pair;
    __syncthreads();
    for (int dd = 1; dd < 256; dd <<= 1) {
        int xv = (t >= dd) ? psc[t - dd] : 0;
        __syncthreads();
        psc[t] += xv;
        __syncthreads();
    }
    int pexc = psc[t] - pair;
    if (t == 255) bksum = atomicAdd(gcnt, psc[255]);
    __syncthreads();
    int gb = bksum;
    base512[2 * t]     = gb + pexc;
    base512[2 * t + 1] = gb + pexc + d0;
    c512[2 * t] = 0; c512[2 * t + 1] = 0;
    __syncthreads();
    for (int i = t; i < total; i += 256) {
        unsigned rec = brec[(size_t)b * SC + i];
        int dl = rec & 511;
        int p = atomicAdd(&c512[dl], 1);
        col[base512[dl] + p] = (int)(rec >> 9);
    }
    __syncthreads();
#pragma unroll
    for (int k = 0; k < 2; k++) {
        int dl = t + k * 256;
        int node = b * 512 + dl;
        if (node < N) { cnt[node] = c512[dl]; rp[node] = base512[dl]; }
    }
}

// ---------- fused agg1 + row-local gemm2 (r14 proven) ----------
// Agg: 16-lane group per node, 4 gathers deep, full concurrency. h -> 4.3 KB
// LDS tile (16 nodes = one MFMA B-frag column set), never HBM. One barrier,
// 2jt x 4ks MFMAs with W2 A-frags (L2-hot), g2 written dis-folded.

__global__ __launch_bounds__(256) void k_agg1_g2(
        const unsigned short* __restrict__ gtab, const int* __restrict__ cnt,
        const int* __restrict__ rp, const int* __restrict__ col,
        const float* __restrict__ b1, const unsigned short* __restrict__ Wb2,
        unsigned short* __restrict__ g2, int N) {
    __shared__ __align__(16) unsigned short hl[16 * LROW];   // 4.3 KB
    int t = threadIdx.x, grp = t >> 4, l16 = t & 15;
    int n0 = blockIdx.x * 16;
    int node = n0 + grp;
    bool valid = (node < N);
    int nc = valid ? node : N - 1;
    const u16x8* G = (const u16x8*)gtab;

    int deg = valid ? cnt[node] : 0;
    float disv = rsqrtf((float)(deg + 1));
    float acc[8];
    {
        u16x8 s = G[(size_t)nc * 16 + l16];     // self-loop term (x dis_v)
#pragma unroll
        for (int j = 0; j < 8; j++) acc[j] = bf2f(s[j]) * disv;
    }
    const int* cb = col + (valid ? rp[node] : 0);
    int i = 0;
    for (; i + 3 < deg; i += 4) {
        int u0 = cb[i], u1 = cb[i + 1], u2 = cb[i + 2], u3 = cb[i + 3];
        u16x8 m0 = G[(size_t)u0 * 16 + l16];
        u16x8 m1 = G[(size_t)u1 * 16 + l16];
        u16x8 m2 = G[(size_t)u2 * 16 + l16];
        u16x8 m3 = G[(size_t)u3 * 16 + l16];
        float d0 = rsqrtf((float)(cnt[u0] + 1));
        float d1 = rsqrtf((float)(cnt[u1] + 1));
        float d2 = rsqrtf((float)(cnt[u2] + 1));
        float d3 = rsqrtf((float)(cnt[u3] + 1));
#pragma unroll
        for (int j = 0; j < 8; j++)
            acc[j] += (bf2f(m0[j]) * d0 + bf2f(m1[j]) * d1)
                    + (bf2f(m2[j]) * d2 + bf2f(m3[j]) * d3);
    }
    for (; i < deg; i++) {
        int u = cb[i];
        u16x8 m = G[(size_t)u * 16 + l16];
        float du = rsqrtf((float)(cnt[u] + 1));
#pragma unroll
        for (int j = 0; j < 8; j++) acc[j] += bf2f(m[j]) * du;
    }
    {
        const float4* B4 = (const float4*)b1;
        float4 bb0 = B4[l16 * 2], bb1 = B4[l16 * 2 + 1];
        float r[8];
        r[0] = fmaf(acc[0], disv, bb0.x); r[1] = fmaf(acc[1], disv, bb0.y);
        r[2] = fmaf(acc[2], disv, bb0.z); r[3] = fmaf(acc[3], disv, bb0.w);
        r[4] = fmaf(acc[4], disv, bb1.x); r[5] = fmaf(acc[5], disv, bb1.y);
        r[6] = fmaf(acc[6], disv, bb1.z); r[7] = fmaf(acc[7], disv, bb1.w);
        u16x8 hv;
#pragma unroll
        for (int j = 0; j < 8; j++)
            hv[j] = valid ? f2bf(fmaxf(r[j], 0.f)) : (unsigned short)0;
        *(u16x8*)&hl[grp * LROW + l16 * 8] = hv;
    }
    __syncthreads();

    // ---- mini-gemm2: B-frags = LDS h rows (node = lane&15), A = W2 ----
    int w = t >> 6, l = t & 63;
    int r16 = l & 15, g4 = l >> 4;
    f32x4 a0 = {}, a1 = {};
    const unsigned short* wr = Wb2 + r16 * D + g4 * 8;
    int xb = r16 * LROW + g4 * 8;
#pragma unroll 1
    for (int ks = 0; ks < 4; ks++) {
        bf16x8 b = *(const bf16x8*)&hl[xb + ks * 32];
        bf16x8 A0 = *(const bf16x8*)(wr + (2 * w) * 16 * D + ks * 32);
        bf16x8 A1 = *(const bf16x8*)(wr + (2 * w + 1) * 16 * D + ks * 32);
        a0 = __builtin_amdgcn_mfma_f32_16x16x32_bf16(A0, b, a0, 0, 0, 0);
        a1 = __builtin_amdgcn_mfma_f32_16x16x32_bf16(A1, b, a1, 0, 0, 0);
    }
    int orow = n0 + r16;
    if (orow < N) {
        float dv = rsqrtf((float)(cnt[orow] + 1));
        ushort4 o0 = { f2bf(a0[0] * dv), f2bf(a0[1] * dv),
                       f2bf(a0[2] * dv), f2bf(a0[3] * dv) };
        ushort4 o1 = { f2bf(a1[0] * dv), f2bf(a1[1] * dv),
                       f2bf(a1[2] * dv), f2bf(a1[3] * dv) };
        *(ushort4*)&g2[(size_t)orow * D + (2 * w) * 16 + g4 * 4] = o0;
        *(ushort4*)&g2[(size_t)orow * D + (2 * w + 1) * 16 + g4 * 4] = o1;
    }
}

// ---------- agg2: final aggregation -> fp32 out (r13 proven shape) ---------
__global__ __launch_bounds__(256) void k_agg2(
        const unsigned short* __restrict__ g2, const int* __restrict__ cnt,
        const int* __restrict__ rp, const int* __restrict__ col,
        const float* __restrict__ b2, float* __restrict__ out, int N) {
    int node = blockIdx.x * 16 + (threadIdx.x >> 4);
    if (node >= N) return;
    int l16 = threadIdx.x & 15;
    const u16x8* G = (const u16x8*)g2;
    int deg = cnt[node];
    float acc[8];
    {
        u16x8 s = G[(size_t)node * 16 + l16];
#pragma unroll
        for (int j = 0; j < 8; j++) acc[j] = bf2f(s[j]);
    }
    const int* cb = col + rp[node];
    int i = 0;
    for (; i + 3 < deg; i += 4) {
        int u0 = cb[i], u1 = cb[i + 1], u2 = cb[i + 2], u3 = cb[i + 3];
        u16x8 m0 = G[(size_t)u0 * 16 + l16];
        u16x8 m1 = G[(size_t)u1 * 16 + l16];
        u16x8 m2 = G[(size_t)u2 * 16 + l16];
        u16x8 m3 = G[(size_t)u3 * 16 + l16];
#pragma unroll
        for (int j = 0; j < 8; j++)
            acc[j] += (bf2f(m0[j]) + bf2f(m1[j])) + (bf2f(m2[j]) + bf2f(m3[j]));
    }
    for (; i < deg; i++) {
        u16x8 m = G[(size_t)cb[i] * 16 + l16];
#pragma unroll
        for (int j = 0; j < 8; j++) acc[j] += bf2f(m[j]);
    }
    float disv = rsqrtf((float)(deg + 1));
    const float4* B4 = (const float4*)b2;
    float4 bb0 = B4[l16 * 2], bb1 = B4[l16 * 2 + 1];
    float4 o0, o1;
    o0.x = fmaf(acc[0], disv, bb0.x); o0.y = fmaf(acc[1], disv, bb0.y);
    o0.z = fmaf(acc[2], disv, bb0.z); o0.w = fmaf(acc[3], disv, bb0.w);
    o1.x = fmaf(acc[4], disv, bb1.x); o1.y = fmaf(acc[5], disv, bb1.y);
    o1.z = fmaf(acc[6], disv, bb1.z); o1.w = fmaf(acc[7], disv, bb1.w);
    ((float4*)out)[(size_t)node * 32 + l16 * 2]     = o0;
    ((float4*)out)[(size_t)node * 32 + l16 * 2 + 1] = o1;
}

// ---------- launch ----------

extern "C" void kernel_launch(void* const* d_in, const int* in_sizes, int n_in,
                              void* d_out, int out_size, void* d_ws, size_t ws_size,
                              hipStream_t stream) {
    const float* x  = (const float*)d_in[0];
    const int*   ei = (const int*)d_in[1];
    const float* W1 = (const float*)d_in[2];
    const float* b1 = (const float*)d_in[3];
    const float* W2 = (const float*)d_in[4];
    const float* b2 = (const float*)d_in[5];
    float* out = (float*)d_out;

    int N = in_sizes[0] / D;
    int E = in_sizes[1] / 2;
    int NBK = (N + 511) >> 9;                // buckets of 512 nodes

    // ws: g 25.6 | g2 25.6 | cnt .4 | rp .4 | col 3.2 | Wb .13
    //   | bcnt ~1KB | gcnt | brec 4  -> ~59.4 MB
    char* w = (char*)d_ws;
    unsigned short* g  = (unsigned short*)w;  size_t off = (size_t)N * D * 2;
    off = (off + 255) & ~(size_t)255;
    unsigned short* g2 = (unsigned short*)(w + off); off += (size_t)N * D * 2;
    off = (off + 255) & ~(size_t)255;
    int* cnt  = (int*)(w + off);             off += (size_t)N * 4;
    off = (off + 255) & ~(size_t)255;
    int* rp   = (int*)(w + off);             off += (size_t)N * 4;
    off = (off + 255) & ~(size_t)255;
    int* col  = (int*)(w + off);             off += (size_t)E * 4;
    off = (off + 255) & ~(size_t)255;
    unsigned short* Wb1 = (unsigned short*)(w + off); off += (size_t)D * D * 2;
    unsigned short* Wb2 = (unsigned short*)(w + off); off += (size_t)D * D * 2;
    off = (off + 255) & ~(size_t)255;
    int* bcnt = (int*)(w + off);             off += (size_t)NBK * 4;
    off = (off + 255) & ~(size_t)255;
    int* gcnt = (int*)(w + off);             off += 256;
    unsigned* brec = (unsigned*)(w + off);   off += (size_t)NBK * SC * 4;

    int ntiles = (N + 127) / 128;            // 782 gemm1 tiles
    int sortB  = (E + BE - 1) / BE;          // 196 sort blocks
    int fb = sortB > (ntiles + 7) / 8 ? sortB : (ntiles + 7) / 8;
    int agg_grid = (N + 15) / 16;

    k_prep<<<(D * D + 511) / 256, 256, 0, stream>>>(W1, W2, Wb1, Wb2, bcnt, gcnt, NBK);

    // K1: sort (ei -> bcnt,brec)  ||  ALL gemm1 (g = bf16(x @ W1^T), raw)
    k_sort_gemm1<<<9 * fb, 256, 0, stream>>>(ei, bcnt, brec, x, Wb1, g,
                                             N, E, ntiles, sortB, NBK);
    // build: brec -> dense CSR (col, rp, cnt)
    k_build<<<NBK, 256, 0, stream>>>(bcnt, brec, cnt, rp, col, gcnt, N);

    // fused agg1 + row-local gemm2: g2 = bf16(dis * (relu(agg1+b1) @ W2^T))
    k_agg1_g2<<<agg_grid, 256, 0, stream>>>(g, cnt, rp, col, b1, Wb2, g2, N);

    // agg2: out = dis_v*(Σ g2[u] + g2[v]) + b2  (fp32) -> d_out
    k_agg2<<<agg_grid, 256, 0, stream>>>(g2, cnt, rp, col, b2, out, N);
}